// Round 1
// baseline (2737.890 us; speedup 1.0000x reference)
//
#include <hip/hip_runtime.h>

// Residual VQ on MI355X.
// z: [8, 32768, 32] f32; codebooks: [10, 512, 32] f32.
// Outputs (flat f32 in d_out): quantized [B,N,D], indices [B,N,Q] (as float),
// commit_loss [Q] (zeros).

#define RVQ_B 8
#define RVQ_N 32768
#define RVQ_D 32
#define RVQ_Q 10
#define RVQ_C 512

static constexpr int  NPTS      = RVQ_B * RVQ_N;            // 262144
static constexpr long QUANT_SZ  = (long)NPTS * RVQ_D;       // 8388608
static constexpr long IDX_OFF   = QUANT_SZ;
static constexpr long IDX_SZ    = (long)NPTS * RVQ_Q;       // 2621440
static constexpr long LOSS_OFF  = IDX_OFF + IDX_SZ;

// ---------------------------------------------------------------------------
// Kernel 1: per-codeword squared norms -> ws[Q*C]
// numpy-style 8-accumulator reduction with pairwise combine.
__global__ void rvq_cb_norms(const float* __restrict__ cb, float* __restrict__ ws) {
    int i = blockIdx.x * blockDim.x + threadIdx.x;
    if (i >= RVQ_Q * RVQ_C) return;
    const float* c = cb + (long)i * RVQ_D;
    float a[8];
#pragma unroll
    for (int j = 0; j < 8; ++j) a[j] = c[j] * c[j];
#pragma unroll
    for (int j = 8; j < RVQ_D; ++j) a[j & 7] = fmaf(c[j], c[j], a[j & 7]);
    ws[i] = ((a[0] + a[1]) + (a[2] + a[3])) + ((a[4] + a[5]) + (a[6] + a[7]));
}

// ---------------------------------------------------------------------------
// Kernel 2: main RVQ. One thread per point; residual in registers.
__global__ __launch_bounds__(256) void rvq_main(const float* __restrict__ z,
                                                const float* __restrict__ cb,
                                                const float* __restrict__ cbn,
                                                float* __restrict__ out) {
    const int p = blockIdx.x * 256 + threadIdx.x;
    const float* zp = z + (long)p * RVQ_D;

    float r[RVQ_D];     // residual
    float oacc[RVQ_D];  // accumulated quantized output (sum of q_st)
#pragma unroll
    for (int d = 0; d < RVQ_D; ++d) { r[d] = zp[d]; oacc[d] = 0.0f; }

    int idxs[RVQ_Q];

#pragma unroll 1
    for (int q = 0; q < RVQ_Q; ++q) {
        // rr = sum(r*r), numpy 8-acc pairwise style
        float a[8];
#pragma unroll
        for (int j = 0; j < 8; ++j) a[j] = r[j] * r[j];
#pragma unroll
        for (int j = 8; j < RVQ_D; ++j) a[j & 7] = fmaf(r[j], r[j], a[j & 7]);
        const float rr = ((a[0] + a[1]) + (a[2] + a[3])) + ((a[4] + a[5]) + (a[6] + a[7]));

        const float* cq  = cb  + (long)q * RVQ_C * RVQ_D;
        const float* nq_ = cbn + q * RVQ_C;

        float best = __builtin_inff();
        int   bidx = 0;

#pragma unroll 2
        for (int k = 0; k < RVQ_C; ++k) {
            const float* c = cq + k * RVQ_D;
            float acc[8];
#pragma unroll
            for (int j = 0; j < 8; ++j) acc[j] = r[j] * c[j];
#pragma unroll
            for (int j = 8; j < RVQ_D; ++j) acc[j & 7] = fmaf(r[j], c[j], acc[j & 7]);
            const float dot = ((acc[0] + acc[1]) + (acc[2] + acc[3])) +
                              ((acc[4] + acc[5]) + (acc[6] + acc[7]));
            // d = (rr - 2*dot) + cc ; 2*dot exact in fp32, fma == sub here
            const float dist = fmaf(-2.0f, dot, rr) + nq_[k];
            if (dist < best) { best = dist; bidx = k; }  // first-min tie-break
        }
        idxs[q] = bidx;

        // faithful straight-through rounding chain:
        // q_st = r + (c - r); out += q_st; r = r - q_st
        const float* cw = cq + bidx * RVQ_D;
#pragma unroll
        for (int d = 0; d < RVQ_D; ++d) {
            const float qst = r[d] + (cw[d] - r[d]);
            oacc[d] += qst;
            r[d] = r[d] - qst;
        }
    }

    // quantized
    float* qo = out + (long)p * RVQ_D;
#pragma unroll
    for (int d = 0; d < RVQ_D; ++d) qo[d] = oacc[d];

    // indices (as float, layout [B,N,Q] -> p*Q + q)
    float* io = out + IDX_OFF + (long)p * RVQ_Q;
#pragma unroll
    for (int q = 0; q < RVQ_Q; ++q) io[q] = (float)idxs[q];

    // commit_loss zeros
    if (p < RVQ_Q) out[LOSS_OFF + p] = 0.0f;
}

// ---------------------------------------------------------------------------
extern "C" void kernel_launch(void* const* d_in, const int* in_sizes, int n_in,
                              void* d_out, int out_size, void* d_ws, size_t ws_size,
                              hipStream_t stream) {
    const float* z  = (const float*)d_in[0];
    const float* cb = (const float*)d_in[1];
    float* out = (float*)d_out;
    float* cbn = (float*)d_ws;  // Q*C floats = 20 KiB

    rvq_cb_norms<<<(RVQ_Q * RVQ_C + 255) / 256, 256, 0, stream>>>(cb, cbn);
    rvq_main<<<NPTS / 256, 256, 0, stream>>>(z, cb, cbn, out);
}